// Round 2
// baseline (248.137 us; speedup 1.0000x reference)
//
#include <hip/hip_runtime.h>

// DigitCaps on MI355X. All tensors FP32 (per the reference; R1's bf16
// interpretation produced NaN = fp32-read-as-bf16 signature).
//
// Sizes: B=128, J=4608 positions, INPUT_D=8, D=8, M=4 -> N=J*M=18432 votes,
// C=10 caps. Output = concat(output[128,10], digit_caps_new[10,8]) fp32.
//
// Math: output[b,c] = mean_n <u[b,n], dc_new[c]> = <(1/N) sum_n u[b,n], dc_new[c]>
// so we only need s[b,:] = sum_n u[b,n,:] (shape [128,8]) plus seg_u/counts.

#define J_POS 4608
#define BATCH 128
#define JT 8            // j's per block
#define WSTRIDE 264     // 256 + 8 pad: float4 reads stay <=2-way bank aliased (free)
#define NVOTES 18432.0f
#define DENOM  2359296.0f   // B * N

__global__ __launch_bounds__(256) void votes_kernel(
    const float* __restrict__ x,   // [B, J, 8]
    const float* __restrict__ w,   // [J, 8, 32]
    const float* __restrict__ dc,  // [10, 8]
    float* __restrict__ ws)        // [0,80): seg_u [80,90): counts [96,1120): s
{
    __shared__ float w_lds[JT * WSTRIDE];
    __shared__ float dc_lds[80];
    __shared__ float seg_lds[90];           // 80 seg_u + 10 counts
    __shared__ float s_lds[BATCH * 8];

    const int t = threadIdx.x;
    const int j0 = blockIdx.x * JT;

    // ---- stage W tile: 8 j * 256 floats each; thread t loads 8 floats (32 B)
    {
        const int idx = t * 8;              // 0..2047
        const int jj = idx >> 8, rem = idx & 255;
        const float4 r0 = *(const float4*)(w + (size_t)j0 * 256 + idx);
        const float4 r1 = *(const float4*)(w + (size_t)j0 * 256 + idx + 4);
        float* dst = &w_lds[jj * WSTRIDE + rem];
        dst[0] = r0.x; dst[1] = r0.y; dst[2] = r0.z; dst[3] = r0.w;
        dst[4] = r1.x; dst[5] = r1.y; dst[6] = r1.z; dst[7] = r1.w;
    }
    if (t < 80) dc_lds[t] = dc[t];
    if (t < 90) seg_lds[t] = 0.f;
    __syncthreads();

    const int jj = t & 7;          // consecutive lanes -> consecutive j: coalesced x
    const int brow = t >> 3;       // 0..31

    #pragma unroll 1
    for (int iter = 0; iter < 4; ++iter) {
        const int b = iter * 32 + brow;

        // ---- load x[b, j0+jj, :] : 8 floats = two 16 B loads
        const float* xp = x + ((size_t)b * J_POS + (j0 + jj)) * 8;
        const float4 x0 = *(const float4*)(xp);
        const float4 x1 = *(const float4*)(xp + 4);
        float xf[8] = { x0.x, x0.y, x0.z, x0.w, x1.x, x1.y, x1.z, x1.w };

        // ---- u[k] = sum_i xf[i] * W[j][i][k],  k = 0..31
        float u[32];
        #pragma unroll
        for (int k = 0; k < 32; ++k) u[k] = 0.f;
        const float* wbase = &w_lds[jj * WSTRIDE];
        #pragma unroll
        for (int i = 0; i < 8; ++i) {
            const float xi = xf[i];
            const float4* wrow = (const float4*)(wbase + i * 32);
            #pragma unroll
            for (int kq = 0; kq < 8; ++kq) {
                const float4 w4 = wrow[kq];
                u[kq * 4 + 0] += xi * w4.x;
                u[kq * 4 + 1] += xi * w4.y;
                u[kq * 4 + 2] += xi * w4.z;
                u[kq * 4 + 3] += xi * w4.w;
            }
        }

        // ---- 4 votes: argmax over 10 caps (strict '>' = first-max, matches jnp.argmax)
        #pragma unroll
        for (int m = 0; m < 4; ++m) {
            float best = -3.402823466e38f;
            int bc = 0;
            #pragma unroll
            for (int c = 0; c < 10; ++c) {
                float sim = 0.f;
                #pragma unroll
                for (int d = 0; d < 8; ++d) sim += u[m * 8 + d] * dc_lds[c * 8 + d];
                if (sim > best) { best = sim; bc = c; }
            }
            #pragma unroll
            for (int d = 0; d < 8; ++d) atomicAdd(&seg_lds[bc * 8 + d], u[m * 8 + d]);
            atomicAdd(&seg_lds[80 + bc], 1.0f);
        }

        // ---- per-b sum of the 4 votes; reduce across the 8 jj-lanes (same wave)
        float su[8];
        #pragma unroll
        for (int d = 0; d < 8; ++d) su[d] = u[d] + u[8 + d] + u[16 + d] + u[24 + d];
        #pragma unroll
        for (int d = 0; d < 8; ++d) {
            su[d] += __shfl_xor(su[d], 1);
            su[d] += __shfl_xor(su[d], 2);
            su[d] += __shfl_xor(su[d], 4);
        }
        if (jj == 0) {
            #pragma unroll
            for (int d = 0; d < 8; ++d) s_lds[b * 8 + d] = su[d];  // unique (b) per block
        }
    }

    __syncthreads();

    // ---- flush block partials to global workspace
    if (t < 90) atomicAdd(&ws[t], seg_lds[t]);
    float* gs = ws + 96;
    #pragma unroll
    for (int r = 0; r < 4; ++r) atomicAdd(&gs[r * 256 + t], s_lds[r * 256 + t]);
}

__global__ __launch_bounds__(256) void finalize_kernel(
    const float* __restrict__ ws,
    const float* __restrict__ dc,
    float* __restrict__ out)       // [0,1280): output  [1280,1360): dc_new
{
    __shared__ float dcn[80];
    const float* seg = ws;
    const float* cnt = ws + 80;
    const float* s   = ws + 96;
    const int t = threadIdx.x;

    if (t < 80) {
        const int c = t >> 3;
        const float d0 = dc[t];
        const float nd = d0 + (seg[t] - cnt[c] * d0) * (1.0f / DENOM);
        dcn[t] = nd;
        out[1280 + t] = nd;
    }
    __syncthreads();

    #pragma unroll
    for (int r = 0; r < 5; ++r) {
        const int idx = r * 256 + t;        // 0..1279
        const int b = idx / 10, c = idx % 10;
        float acc = 0.f;
        #pragma unroll
        for (int d = 0; d < 8; ++d) acc += s[b * 8 + d] * dcn[c * 8 + d];
        out[idx] = acc * (1.0f / NVOTES);
    }
}

extern "C" void kernel_launch(void* const* d_in, const int* in_sizes, int n_in,
                              void* d_out, int out_size, void* d_ws, size_t ws_size,
                              hipStream_t stream) {
    const float* x  = (const float*)d_in[0];
    const float* w  = (const float*)d_in[1];
    const float* dc = (const float*)d_in[2];
    float* out = (float*)d_out;
    float* ws = (float*)d_ws;

    // zero seg_u/counts/s accumulators (1120 floats)
    hipMemsetAsync(d_ws, 0, 1120 * sizeof(float), stream);

    votes_kernel<<<J_POS / JT, 256, 0, stream>>>(x, w, dc, ws);
    finalize_kernel<<<1, 256, 0, stream>>>(ws, dc, out);
}

// Round 4
// 136.210 us; speedup vs baseline: 1.8217x; 1.8217x over previous
//
#include <hip/hip_runtime.h>

// DigitCaps on MI355X, fp32 I/O, R4.
// R2 lesson: fp32 atomicAdd = CAS-loop disaster -> native int atomics only.
// R3 lesson: winners' u are BIASED toward dc_c (argmax selects them), so
// seg_u[c,d] ~ 3e5; at fixed-point scale 2^17 the global int32 accumulator
// wrapped (~4e10 > 2^31) -> dc_new absmax 0.18. Fix: LDS int32 @ 2^15
// (per-block max ~4e8, safe), global accumulator int64 (exact, never wraps).
//
// Sizes: B=128, J=4608, INPUT_D=8, D=8, M=4 -> N=18432 votes, C=10.
// Output = concat(output[128,10], digit_caps_new[10,8]).
// Math: output[b,c] = <(1/N) sum_n u[b,n], dc_new[c]> -> only s[b,:]=sum_n u needed.
//
// ws layout (4B units):
//   i64  [0, 80)   as 160 ints     seg accumulators (fixed-point 2^15), index c*8+d
//   int  [160,170)                 counts per cap
//   float[1024, 1024+576*1024)     per-block s partials [blk][128*8]  (~2.36 MB)

#define J_POS 4608
#define NBLK  576
#define JT 8
#define WSTRIDE 264     // 256+8 pad
#define NVOTES 18432.0f
#define DENOM  2359296.0f       // B*N
#define SEG_SCALE 32768.0f      // 2^15
#define INV_SEG_SCALE 3.0517578125e-5f

__global__ __launch_bounds__(256) void votes_kernel(
    const float* __restrict__ x,   // [B, J, 8]
    const float* __restrict__ w,   // [J, 8, 32]
    const float* __restrict__ dc,  // [10, 8]
    unsigned long long* __restrict__ ws64,  // seg int64 [80]
    int*  __restrict__ wsi,        // counts at [160,170)
    float* __restrict__ wsf)       // s partials from 1024
{
    __shared__ float w_lds[JT * WSTRIDE];
    __shared__ float dc_lds[80];
    __shared__ int   seg_lds[2][96];   // replica: index c*9+d (d<8) / c*9+8 = count
    __shared__ float s_lds[128 * 8];

    const int t = threadIdx.x;
    const int j0 = blockIdx.x * JT;

    // ---- stage W tile: 8 j * 256 floats; thread t loads 8 floats
    {
        const int idx = t * 8;
        const int jj = idx >> 8, rem = idx & 255;
        const float4 r0 = *(const float4*)(w + (size_t)j0 * 256 + idx);
        const float4 r1 = *(const float4*)(w + (size_t)j0 * 256 + idx + 4);
        float* dst = &w_lds[jj * WSTRIDE + rem];
        dst[0] = r0.x; dst[1] = r0.y; dst[2] = r0.z; dst[3] = r0.w;
        dst[4] = r1.x; dst[5] = r1.y; dst[6] = r1.z; dst[7] = r1.w;
    }
    if (t < 80) dc_lds[t] = dc[t];
    if (t < 192) (&seg_lds[0][0])[t] = 0;
    __syncthreads();

    const int jj = t & 7;          // consecutive lanes -> consecutive j: coalesced x
    const int brow = t >> 3;       // 0..31
    int* const segp = seg_lds[(t >> 5) & 1];   // half-wave replicas halve same-address multiplicity

    #pragma unroll 1
    for (int iter = 0; iter < 4; ++iter) {
        const int b = iter * 32 + brow;

        const float* xp = x + ((size_t)b * J_POS + (j0 + jj)) * 8;
        const float4 x0 = *(const float4*)(xp);
        const float4 x1 = *(const float4*)(xp + 4);
        float xf[8] = { x0.x, x0.y, x0.z, x0.w, x1.x, x1.y, x1.z, x1.w };

        // ---- u[k] = sum_i xf[i] * W[j][i][k]
        float u[32];
        #pragma unroll
        for (int k = 0; k < 32; ++k) u[k] = 0.f;
        const float* wbase = &w_lds[jj * WSTRIDE];
        #pragma unroll
        for (int i = 0; i < 8; ++i) {
            const float xi = xf[i];
            const float4* wrow = (const float4*)(wbase + i * 32);
            #pragma unroll
            for (int kq = 0; kq < 8; ++kq) {
                const float4 w4 = wrow[kq];
                u[kq * 4 + 0] += xi * w4.x;
                u[kq * 4 + 1] += xi * w4.y;
                u[kq * 4 + 2] += xi * w4.z;
                u[kq * 4 + 3] += xi * w4.w;
            }
        }

        // ---- 4 votes: argmax over 10 caps (strict '>' = first-max, matches jnp.argmax)
        #pragma unroll
        for (int m = 0; m < 4; ++m) {
            float best = -3.402823466e38f;
            int bc = 0;
            #pragma unroll
            for (int c = 0; c < 10; ++c) {
                float sim = 0.f;
                #pragma unroll
                for (int d = 0; d < 8; ++d) sim += u[m * 8 + d] * dc_lds[c * 8 + d];
                if (sim > best) { best = sim; bc = c; }
            }
            // native int LDS atomics, fire-and-forget
            #pragma unroll
            for (int d = 0; d < 8; ++d)
                atomicAdd(&segp[bc * 9 + d], __float2int_rn(u[m * 8 + d] * SEG_SCALE));
            atomicAdd(&segp[bc * 9 + 8], 1);
        }

        // ---- per-b sum of the 4 votes; reduce across the 8 jj-lanes (same wave)
        float su[8];
        #pragma unroll
        for (int d = 0; d < 8; ++d) su[d] = u[d] + u[8 + d] + u[16 + d] + u[24 + d];
        #pragma unroll
        for (int d = 0; d < 8; ++d) {
            su[d] += __shfl_xor(su[d], 1);
            su[d] += __shfl_xor(su[d], 2);
            su[d] += __shfl_xor(su[d], 4);
        }
        if (jj == 0) {
            #pragma unroll
            for (int d = 0; d < 8; ++d) s_lds[b * 8 + d] = su[d];
        }
    }

    __syncthreads();

    // ---- flush: seg -> int64 global atomics (exact), counts -> int32, s -> plain store
    if (t < 80) {
        const int c = t >> 3, d = t & 7;
        const long long v = (long long)(seg_lds[0][c * 9 + d] + seg_lds[1][c * 9 + d]);
        atomicAdd(&ws64[t], (unsigned long long)v);
    } else if (t < 90) {
        const int c = t - 80;
        atomicAdd(&wsi[160 + c], seg_lds[0][c * 9 + 8] + seg_lds[1][c * 9 + 8]);
    }
    const float4 sv = *(const float4*)&s_lds[t * 4];
    *(float4*)&wsf[1024 + (size_t)blockIdx.x * 1024 + t * 4] = sv;
}

// one block per batch row b; reduces s partials, computes dc_new + output row
__global__ __launch_bounds__(256) void finalize_kernel(
    const unsigned long long* __restrict__ ws64,
    const int*  __restrict__ wsi,
    const float* __restrict__ wsf,
    const float* __restrict__ dc,
    float* __restrict__ out)       // [0,1280): output  [1280,1360): dc_new
{
    __shared__ float dcn[80];
    __shared__ float red[32][8];
    __shared__ float srow[8];
    const int t = threadIdx.x;
    const int b = blockIdx.x;

    if (t < 80) {
        const int c = t >> 3;
        const float segf = (float)(long long)ws64[t] * INV_SEG_SCALE;
        const float cntf = (float)wsi[160 + c];
        const float d0 = dc[t];
        const float nd = d0 + (segf - cntf * d0) * (1.0f / DENOM);
        dcn[t] = nd;
        if (b == 0) out[1280 + t] = nd;
    }
    {
        const int kg = t >> 3, d = t & 7;    // 32 k-groups x 8 d
        float acc = 0.f;
        #pragma unroll
        for (int i = 0; i < 18; ++i)         // 576 = 32*18
            acc += wsf[1024 + (size_t)(kg + 32 * i) * 1024 + b * 8 + d];
        red[kg][d] = acc;
    }
    __syncthreads();
    if (t < 8) {
        float a = 0.f;
        #pragma unroll
        for (int kg = 0; kg < 32; ++kg) a += red[kg][t];
        srow[t] = a;
    }
    __syncthreads();
    if (t < 10) {
        float acc = 0.f;
        #pragma unroll
        for (int d = 0; d < 8; ++d) acc += srow[d] * dcn[t * 8 + d];
        out[b * 10 + t] = acc * (1.0f / NVOTES);
    }
}

extern "C" void kernel_launch(void* const* d_in, const int* in_sizes, int n_in,
                              void* d_out, int out_size, void* d_ws, size_t ws_size,
                              hipStream_t stream) {
    const float* x  = (const float*)d_in[0];
    const float* w  = (const float*)d_in[1];
    const float* dc = (const float*)d_in[2];
    float* out = (float*)d_out;
    unsigned long long* ws64 = (unsigned long long*)d_ws;
    int*   wsi = (int*)d_ws;
    float* wsf = (float*)d_ws;

    // zero seg64 (160 ints) + counts (10 ints); round up to 1024 ints
    hipMemsetAsync(d_ws, 0, 1024 * sizeof(int), stream);
    votes_kernel<<<NBLK, 256, 0, stream>>>(x, w, dc, ws64, wsi, wsf);
    finalize_kernel<<<128, 256, 0, stream>>>(ws64, wsi, wsf, dc, out);
}